// Round 7
// baseline (55.682 us; speedup 1.0000x reference)
//
#include <hip/hip_runtime.h>
#include <hip/hip_bf16.h>

// B=8, H=64, W=64, C=256, NUM_HEADS=8, dph=32, DIL=3, k2=9
// qkv GEMM: Y[32768,768] = X[32768,256] @ W[768,256]^T in bf16 MFMA.
// ws layout (ushort units): xb[8388608] | wb[196608] | qkv[25165824]  (67.5 MB)

typedef unsigned short ushortT;
typedef __attribute__((ext_vector_type(8))) short short8;
typedef __attribute__((ext_vector_type(4))) float f32x4;

__device__ __forceinline__ ushortT f2b(float f) {  // RTNE f32 -> bf16 bits
    unsigned u = __float_as_uint(f);
    return (ushortT)((u + 0x7fffu + ((u >> 16) & 1u)) >> 16);
}
__device__ __forceinline__ float b2f(ushortT u) {
    return __uint_as_float((unsigned)u << 16);
}

// ---- convert x [8388608 f32] and W [196608 f32] to bf16 ----
__global__ __launch_bounds__(256) void to_bf16(const float* __restrict__ x,
                                               const float* __restrict__ wq,
                                               ushortT* __restrict__ xb,
                                               ushortT* __restrict__ wb) {
    const int N4X = 2097152, N4W = 49152;
    int i = blockIdx.x * 256 + threadIdx.x;
    if (i < N4X) {
        float4 f = ((const float4*)x)[i];
        ushort4 u = {f2b(f.x), f2b(f.y), f2b(f.z), f2b(f.w)};
        ((ushort4*)xb)[i] = u;
    } else {
        int j = i - N4X;
        if (j < N4W) {
            float4 f = ((const float4*)wq)[j];
            ushort4 u = {f2b(f.x), f2b(f.y), f2b(f.z), f2b(f.w)};
            ((ushort4*)wb)[j] = u;
        }
    }
}

// ---- bf16 MFMA GEMM: 128x128 tile, BK=32, DOUBLE-buffered LDS (2-phase T3-min) ----
// LDS 32KB total: As0|Bs0|As1|Bs1, 8KB each ([128 rows][4 slots of 16B]).
// Swizzle: slot' = slot ^ ((row>>1)&3), carried on global source (G21), <=2-way on reads.
// Per iter: issue next tile's 4 global_load_lds, compute current (8 ds_read + 16 MFMA),
// then ONE vmcnt-drain barrier. Load latency hides under compute.
// Epilogue: repack C through the full 32KB (128x128 bf16) -> coalesced 16B stores.
__global__ __launch_bounds__(256) void gemm_qkv(const ushortT* __restrict__ A,
                                                const ushortT* __restrict__ Bw,
                                                ushortT* __restrict__ Y) {
    __shared__ __align__(16) ushortT smem[16384];  // 32KB

    // XCD-chunked swizzle: 1536 blocks, 8 XCDs, 192 per XCD (bijective).
    int bid = blockIdx.x;
    int swz = (bid & 7) * 192 + (bid >> 3);
    int mblk = swz / 6, nblk = swz - mblk * 6;
    const int m0 = mblk * 128, n0 = nblk * 128;

    const int t = threadIdx.x;
    const int lane = t & 63, wv = t >> 6;
    const int wm = (wv >> 1) * 64, wn = (wv & 1) * 64;
    const int lr = lane & 15, g = lane >> 4;
    const int srow = t >> 2, sslot = t & 3;      // staging: 64 rows/pass, 4 slots of 16B
    const int wvb = (t & ~63) * 8;               // wave-uniform dest base (ushort units)

    f32x4 acc[4][4] = {};

    // STAGE one 128x32 A-tile + B-tile into buffer at ushort offset `bo`.
#define STAGE(bo, k0)                                                                 \
    do {                                                                              \
        _Pragma("unroll")                                                             \
        for (int p = 0; p < 2; ++p) {                                                 \
            int row = p * 64 + srow;                                                  \
            int ss = sslot ^ ((row >> 1) & 3);                                        \
            const ushortT* ga = A + (size_t)(m0 + row) * 256 + (k0) + ss * 8;         \
            __builtin_amdgcn_global_load_lds(                                         \
                (const __attribute__((address_space(1))) unsigned int*)ga,            \
                (__attribute__((address_space(3))) unsigned int*)(smem + (bo) + p * 2048 + wvb), \
                16, 0, 0);                                                            \
            const ushortT* gb = Bw + (size_t)(n0 + row) * 256 + (k0) + ss * 8;        \
            __builtin_amdgcn_global_load_lds(                                         \
                (const __attribute__((address_space(1))) unsigned int*)gb,            \
                (__attribute__((address_space(3))) unsigned int*)(smem + (bo) + 4096 + p * 2048 + wvb), \
                16, 0, 0);                                                            \
        }                                                                             \
    } while (0)

    STAGE(0, 0);
    __syncthreads();  // drain prologue loads

#pragma unroll
    for (int ks = 0; ks < 8; ++ks) {
        const int cur = (ks & 1) * 8192;
        const int nxt = 8192 - cur;
        if (ks < 7) STAGE(nxt, (ks + 1) * 32);  // issue next tile early (overlaps compute)

        short8 af[4], bfr[4];
#pragma unroll
        for (int mi = 0; mi < 4; ++mi) {
            int row = wm + mi * 16 + lr;
            int slot = g ^ ((row >> 1) & 3);
            af[mi] = *(const short8*)&smem[cur + row * 32 + slot * 8];
        }
#pragma unroll
        for (int ni = 0; ni < 4; ++ni) {
            int row = wn + ni * 16 + lr;
            int slot = g ^ ((row >> 1) & 3);
            bfr[ni] = *(const short8*)&smem[cur + 4096 + row * 32 + slot * 8];
        }
#pragma unroll
        for (int mi = 0; mi < 4; ++mi)
#pragma unroll
            for (int ni = 0; ni < 4; ++ni)
                acc[mi][ni] = __builtin_amdgcn_mfma_f32_16x16x32_bf16(
                    af[mi], bfr[ni], acc[mi][ni], 0, 0, 0);

        __syncthreads();  // one drain+barrier per K-step (compiler emits vmcnt/lgkm)
    }
#undef STAGE

    // ---- epilogue: acc -> LDS (bf16, swizzled) -> coalesced 16B stores ----
    // C/D layout: col = lane&15, row = (lane>>4)*4 + reg
#pragma unroll
    for (int mi = 0; mi < 4; ++mi)
#pragma unroll
        for (int ni = 0; ni < 4; ++ni) {
            int col = wn + ni * 16 + lr;
#pragma unroll
            for (int rg = 0; rg < 4; ++rg) {
                int row = wm + mi * 16 + g * 4 + rg;
                int sc = col ^ (((row >> 2) & 3) << 4);
                smem[row * 128 + sc] = f2b(acc[mi][ni][rg]);
            }
        }
    __syncthreads();
#pragma unroll
    for (int p = 0; p < 8; ++p) {
        int cid = p * 256 + t;          // 0..2047
        int row = cid >> 4;             // 0..127
        int c0 = (cid & 15) * 8;        // 0..120
        int sc0 = c0 ^ (((row >> 2) & 3) << 4);
        short8 vv = *(const short8*)&smem[row * 128 + sc0];
        *(short8*)&Y[(size_t)(m0 + row) * 768 + n0 + c0] = vv;
    }
}

// ---- attention: 2 pixels per wave; lane owns 8 channels (head = (lane&31)>>2) ----
// Dot-reduce = 2 shfl_xor within 4-lane group. All loads 16B/lane coalesced.
__global__ __launch_bounds__(256) void attn3(const ushortT* __restrict__ qkv,
                                             float* __restrict__ out) {
    const float scale = 0.17677669529663689f;  // 1/sqrt(32)
    int bid = blockIdx.x;
    int sbid = (bid & 7) * 512 + (bid >> 3);   // XCD-chunk swizzle (bijective)
    const int t = threadIdx.x;
    const int wpair = sbid * 4 + (t >> 6);     // 0..16383
    const int half = (t >> 5) & 1;
    const int l = t & 31;                      // lane within pixel
    const int wid = wpair * 2 + half;          // pixel 0..32767
    const int b = wid >> 12, pix = wid & 4095;
    const int h = pix >> 6, w = pix & 63;

    const size_t pbase = (size_t)wid * 768;
    short8 qu = *(const short8*)&qkv[pbase + l * 8];
    float q[8];
#pragma unroll
    for (int c = 0; c < 8; ++c) q[c] = b2f((ushortT)qu[c]) * scale;

    float s[9];
    short8 vu[9];
#pragma unroll
    for (int i = 0; i < 3; ++i) {
#pragma unroll
        for (int j = 0; j < 3; ++j) {
            const int kk = i * 3 + j;
            const int hh = h + (i - 1) * 3;
            const int ww = w + (j - 1) * 3;
            float p = 0.f;
            short8 z = {0, 0, 0, 0, 0, 0, 0, 0};
            vu[kk] = z;
            if ((unsigned)hh < 64u && (unsigned)ww < 64u) {
                const size_t nb = ((size_t)((b << 12) + (hh << 6) + ww)) * 768;
                short8 ku = *(const short8*)&qkv[nb + 256 + l * 8];
                vu[kk] = *(const short8*)&qkv[nb + 512 + l * 8];
#pragma unroll
                for (int c = 0; c < 8; ++c) p = fmaf(q[c], b2f((ushortT)ku[c]), p);
            }
            p += __shfl_xor(p, 1);
            p += __shfl_xor(p, 2);  // 4-lane (one head) reduce
            s[kk] = p;
        }
    }

    float m = s[0];
#pragma unroll
    for (int kk = 1; kk < 9; ++kk) m = fmaxf(m, s[kk]);
    float denom = 0.f;
    float o[8] = {};
#pragma unroll
    for (int kk = 0; kk < 9; ++kk) {
        float e = __expf(s[kk] - m);
        denom += e;
#pragma unroll
        for (int c = 0; c < 8; ++c) o[c] = fmaf(e, b2f((ushortT)vu[kk][c]), o[c]);
    }
    const float inv = 1.0f / denom;
    float* op = &out[(size_t)wid * 256 + l * 8];
    float4 o0 = make_float4(o[0] * inv, o[1] * inv, o[2] * inv, o[3] * inv);
    float4 o1 = make_float4(o[4] * inv, o[5] * inv, o[6] * inv, o[7] * inv);
    *(float4*)op = o0;
    *(float4*)(op + 4) = o1;
}

extern "C" void kernel_launch(void* const* d_in, const int* in_sizes, int n_in,
                              void* d_out, int out_size, void* d_ws, size_t ws_size,
                              hipStream_t stream) {
    const float* x  = (const float*)d_in[0];   // [8,64,64,256]
    const float* Wq = (const float*)d_in[1];   // [768,256]
    float* out = (float*)d_out;                // [8,64,64,256]

    ushortT* xb  = (ushortT*)d_ws;             // [32768,256] bf16
    ushortT* wb  = xb + (size_t)8388608;       // [768,256]  bf16
    ushortT* qkv = wb + (size_t)196608;        // [32768,768] bf16

    to_bf16<<<8384, 256, 0, stream>>>(x, Wq, xb, wb);
    gemm_qkv<<<1536, 256, 0, stream>>>(xb, wb, qkv);
    attn3<<<4096, 256, 0, stream>>>(qkv, out);
}